// Round 1
// baseline (103.025 us; speedup 1.0000x reference)
//
#include <hip/hip_runtime.h>

#define S_TOTAL 8192
#define D_DIM   128
#define QBLK    64
#define KVBLK   64
#define QTILES  (S_TOTAL / QBLK)   // 128

typedef __attribute__((ext_vector_type(8))) short bf16x8;
typedef __attribute__((ext_vector_type(4))) float f32x4;

static __device__ __forceinline__ unsigned short f2bf(float f) {
    unsigned int u = __builtin_bit_cast(unsigned int, f);
    u += 0x7FFFu + ((u >> 16) & 1u);   // RNE
    return (unsigned short)(u >> 16);
}

// ---------------------------------------------------------------------------
// attn_partial: one block = (q-tile, kv-split). 4 waves x 16 q-rows.
// Writes final output if nsplit==1, else unnormalized partial (O, m, l).
// ---------------------------------------------------------------------------
__global__ __launch_bounds__(256, 2)
void attn_partial(const float* __restrict__ Qg, const float* __restrict__ Kg,
                  const float* __restrict__ Vg, float* __restrict__ Og,
                  float* __restrict__ Opart, float* __restrict__ mpart,
                  float* __restrict__ lpart)
{
    __shared__ unsigned short sK [KVBLK * 128];   // [k][d], 16B-XOR swizzled
    __shared__ unsigned short sVt[128 * KVBLK];   // [d][k], 16B-XOR swizzled
    __shared__ unsigned short sP [4 * 16 * 72];   // per-wave P relayout, pitch 72

    const int nsplit = (int)gridDim.x;
    const int split  = (int)blockIdx.x;
    const int qt     = (int)gridDim.y - 1 - (int)blockIdx.y;  // longest blocks first
    const int tid    = threadIdx.x;
    const int w      = tid >> 6;
    const int lane   = tid & 63;
    const int g      = lane >> 4;   // 0..3
    const int lr     = lane & 15;   // 0..15

    const int qrow_base  = qt * QBLK + w * 16 + g * 4;  // + r (C-layout rows)
    const int q_frag_row = qt * QBLK + w * 16 + lr;     // A-layout row

    // Q fragments in registers: A-layout (row=lr, k = dc*32 + g*8 + i)
    bf16x8 qa[4];
    #pragma unroll
    for (int dc = 0; dc < 4; ++dc) {
        const float* src = Qg + q_frag_row * D_DIM + dc * 32 + g * 8;
        bf16x8 v;
        #pragma unroll
        for (int i = 0; i < 8; ++i) v[i] = (short)f2bf(src[i]);
        qa[dc] = v;
    }

    f32x4 acc[8];
    #pragma unroll
    for (int dj = 0; dj < 8; ++dj) acc[dj] = f32x4{0.f, 0.f, 0.f, 0.f};
    float m_run[4], l_run[4];
    #pragma unroll
    for (int r = 0; r < 4; ++r) { m_run[r] = -INFINITY; l_run[r] = 0.0f; }

    const float scale = 0.08838834764831845f;  // 1/sqrt(128)
    const int jtiles = qt + 1;

    unsigned short* sPw = sP + w * (16 * 72);
    char* sKc = reinterpret_cast<char*>(sK);
    char* sVc = reinterpret_cast<char*>(sVt);

    for (int j = split; j < jtiles; j += nsplit) {
        __syncthreads();
        // ---- stage K tile [64][128] fp32 -> bf16, swizzled ----
        #pragma unroll
        for (int it = 0; it < 8; ++it) {
            int flat4 = it * 256 + tid;          // 2048 float4s
            int r  = flat4 >> 5;                 // 0..63
            int d0 = (flat4 & 31) << 2;          // 0..124
            const float4 kv = *reinterpret_cast<const float4*>(
                Kg + (j * KVBLK + r) * D_DIM + d0);
            ushort4 wv;
            wv.x = f2bf(kv.x); wv.y = f2bf(kv.y); wv.z = f2bf(kv.z); wv.w = f2bf(kv.w);
            int byte = (r << 8) | (((d0 >> 3) ^ (r & 15)) << 4) | ((d0 & 7) << 1);
            *reinterpret_cast<ushort4*>(sKc + byte) = wv;
        }
        // ---- stage V tile transposed [d][k], swizzled ----
        {
            int d = tid & 127;
            int khalf = tid >> 7;
            #pragma unroll
            for (int it = 0; it < 8; ++it) {
                int k0 = it * 8 + khalf * 4;     // 0..60
                const float* vsrc = Vg + (j * KVBLK + k0) * D_DIM + d;
                float a0 = vsrc[0 * D_DIM], a1 = vsrc[1 * D_DIM];
                float a2 = vsrc[2 * D_DIM], a3 = vsrc[3 * D_DIM];
                ushort4 wv;
                wv.x = f2bf(a0); wv.y = f2bf(a1); wv.z = f2bf(a2); wv.w = f2bf(a3);
                int byte = (d << 7) | (((k0 >> 3) ^ (d & 7)) << 4) | ((k0 & 7) << 1);
                *reinterpret_cast<ushort4*>(sVc + byte) = wv;
            }
        }
        __syncthreads();

        // ---- QK^T: 4 kj-tiles x 4 d-chunks ----
        f32x4 sf[4];
        #pragma unroll
        for (int kj = 0; kj < 4; ++kj) {
            f32x4 accs = f32x4{0.f, 0.f, 0.f, 0.f};
            #pragma unroll
            for (int dc = 0; dc < 4; ++dc) {
                int rowk = kj * 16 + lr;
                int slot = (dc * 4 + g) ^ lr;
                bf16x8 b = *reinterpret_cast<bf16x8*>(sKc + ((rowk << 8) | (slot << 4)));
                accs = __builtin_amdgcn_mfma_f32_16x16x32_bf16(qa[dc], b, accs, 0, 0, 0);
            }
            sf[kj] = accs;
        }

        // ---- scale + causal mask (only diagonal tile is partial) ----
        #pragma unroll
        for (int kj = 0; kj < 4; ++kj)
            #pragma unroll
            for (int r = 0; r < 4; ++r)
                sf[kj][r] *= scale;
        if (j == qt) {
            #pragma unroll
            for (int kj = 0; kj < 4; ++kj) {
                int kglob = j * KVBLK + kj * 16 + lr;
                #pragma unroll
                for (int r = 0; r < 4; ++r)
                    if (kglob > qrow_base + r) sf[kj][r] = -INFINITY;
            }
        }

        // ---- online softmax (row reduce across 16 lanes of group) ----
        float tmax[4];
        #pragma unroll
        for (int r = 0; r < 4; ++r)
            tmax[r] = fmaxf(fmaxf(sf[0][r], sf[1][r]), fmaxf(sf[2][r], sf[3][r]));
        #pragma unroll
        for (int off = 1; off < 16; off <<= 1)
            #pragma unroll
            for (int r = 0; r < 4; ++r)
                tmax[r] = fmaxf(tmax[r], __shfl_xor(tmax[r], off));

        float fsc[4], lt[4];
        #pragma unroll
        for (int r = 0; r < 4; ++r) {
            float mn = fmaxf(m_run[r], tmax[r]);
            fsc[r] = __expf(m_run[r] - mn);
            m_run[r] = mn;
            lt[r] = 0.0f;
        }
        #pragma unroll
        for (int kj = 0; kj < 4; ++kj)
            #pragma unroll
            for (int r = 0; r < 4; ++r) {
                float p = __expf(sf[kj][r] - m_run[r]);
                sf[kj][r] = p;
                lt[r] += p;
            }
        #pragma unroll
        for (int off = 1; off < 16; off <<= 1)
            #pragma unroll
            for (int r = 0; r < 4; ++r)
                lt[r] += __shfl_xor(lt[r], off);
        #pragma unroll
        for (int r = 0; r < 4; ++r)
            l_run[r] = l_run[r] * fsc[r] + lt[r];
        #pragma unroll
        for (int dj = 0; dj < 8; ++dj)
            #pragma unroll
            for (int r = 0; r < 4; ++r)
                acc[dj][r] *= fsc[r];

        // ---- P: C-layout -> LDS -> A-layout fragments ----
        #pragma unroll
        for (int kj = 0; kj < 4; ++kj)
            #pragma unroll
            for (int r = 0; r < 4; ++r)
                sPw[(g * 4 + r) * 72 + kj * 16 + lr] = f2bf(sf[kj][r]);
        bf16x8 pa[2];
        #pragma unroll
        for (int kc = 0; kc < 2; ++kc)
            pa[kc] = *reinterpret_cast<bf16x8*>(sPw + lr * 72 + kc * 32 + g * 8);

        // ---- PV: 8 d-tiles x 2 k-chunks ----
        #pragma unroll
        for (int dj = 0; dj < 8; ++dj) {
            #pragma unroll
            for (int kc = 0; kc < 2; ++kc) {
                int d = dj * 16 + lr;
                int slot = (kc * 4 + g) ^ (lr & 7);
                bf16x8 b = *reinterpret_cast<bf16x8*>(sVc + ((d << 7) | (slot << 4)));
                acc[dj] = __builtin_amdgcn_mfma_f32_16x16x32_bf16(pa[kc], b, acc[dj], 0, 0, 0);
            }
        }
    }

    // ---- epilogue ----
    if (nsplit == 1) {
        #pragma unroll
        for (int r = 0; r < 4; ++r) {
            float inv = 1.0f / l_run[r];
            int row = qrow_base + r;
            #pragma unroll
            for (int dj = 0; dj < 8; ++dj)
                Og[row * D_DIM + dj * 16 + lr] = acc[dj][r] * inv;
        }
    } else {
        int pidx = qt * nsplit + split;
        float* Ob = Opart + (size_t)pidx * (QBLK * D_DIM);
        #pragma unroll
        for (int r = 0; r < 4; ++r) {
            int row = w * 16 + g * 4 + r;
            #pragma unroll
            for (int dj = 0; dj < 8; ++dj)
                Ob[row * D_DIM + dj * 16 + lr] = acc[dj][r];
        }
        if (lr == 0) {
            #pragma unroll
            for (int r = 0; r < 4; ++r) {
                mpart[pidx * QBLK + w * 16 + g * 4 + r] = m_run[r];
                lpart[pidx * QBLK + w * 16 + g * 4 + r] = l_run[r];
            }
        }
    }
}

// ---------------------------------------------------------------------------
// merge: combine nsplit partials per q-tile.
// ---------------------------------------------------------------------------
__global__ __launch_bounds__(256)
void attn_merge(const float* __restrict__ Opart, const float* __restrict__ mpart,
                const float* __restrict__ lpart, float* __restrict__ Og, int nsplit)
{
    int qt  = blockIdx.x;
    int tid = threadIdx.x;
    int r   = tid >> 2;          // 0..63
    int c0  = (tid & 3) * 32;    // 4 threads per row

    float M = -INFINITY;
    for (int s = 0; s < nsplit; ++s)
        M = fmaxf(M, mpart[(qt * nsplit + s) * QBLK + r]);
    float e[4];
    float L = 0.0f;
    for (int s = 0; s < nsplit; ++s) {
        e[s] = __expf(mpart[(qt * nsplit + s) * QBLK + r] - M);
        L += e[s] * lpart[(qt * nsplit + s) * QBLK + r];
    }
    float invL = 1.0f / L;

    for (int c4 = 0; c4 < 8; ++c4) {
        float ax = 0.f, ay = 0.f, az = 0.f, aw = 0.f;
        for (int s = 0; s < nsplit; ++s) {
            const float4 o = *reinterpret_cast<const float4*>(
                Opart + ((size_t)(qt * nsplit + s) * QBLK + r) * D_DIM + c0 + c4 * 4);
            ax += e[s] * o.x; ay += e[s] * o.y; az += e[s] * o.z; aw += e[s] * o.w;
        }
        float4 outv = { ax * invL, ay * invL, az * invL, aw * invL };
        *reinterpret_cast<float4*>(Og + ((size_t)qt * QBLK + r) * D_DIM + c0 + c4 * 4) = outv;
    }
}

// ---------------------------------------------------------------------------
extern "C" void kernel_launch(void* const* d_in, const int* in_sizes, int n_in,
                              void* d_out, int out_size, void* d_ws, size_t ws_size,
                              hipStream_t stream)
{
    const float* Qg = (const float*)d_in[0];
    const float* Kg = (const float*)d_in[1];
    const float* Vg = (const float*)d_in[2];
    float* Og = (float*)d_out;

    int nsplit = 4;
    auto need = [](int n) -> size_t {
        // per split-unit: O (64*128 f32) + m,l (64 f32 each) per q-tile
        return (size_t)n * QTILES * ((size_t)QBLK * D_DIM * 4 + (size_t)QBLK * 8);
    };
    while (nsplit > 1 && (d_ws == nullptr || ws_size < need(nsplit))) nsplit >>= 1;

    float* Opart = (float*)d_ws;
    float* mpart = (nsplit > 1) ? Opart + (size_t)QTILES * nsplit * QBLK * D_DIM : nullptr;
    float* lpart = (nsplit > 1) ? mpart + (size_t)QTILES * nsplit * QBLK : nullptr;

    dim3 grid(nsplit, QTILES), block(256);
    hipLaunchKernelGGL(attn_partial, grid, block, 0, stream,
                       Qg, Kg, Vg, Og, Opart, mpart, lpart);
    if (nsplit > 1)
        hipLaunchKernelGGL(attn_merge, dim3(QTILES), dim3(256), 0, stream,
                           Opart, mpart, lpart, Og, nsplit);
}

// Round 2
// 76.083 us; speedup vs baseline: 1.3541x; 1.3541x over previous
//
#include <hip/hip_runtime.h>

#define S_TOTAL 8192
#define D_DIM   128
#define QBLK    64
#define KVBLK   64
#define QTILES  128
#define TILEB   16384   // one bf16 K or V tile in bytes (64*128*2)

typedef __attribute__((ext_vector_type(8))) short bf16x8;
typedef __attribute__((ext_vector_type(4))) float f32x4;

static __device__ __forceinline__ unsigned short f2bf(float f) {
    unsigned int u = __builtin_bit_cast(unsigned int, f);
    u += 0x7FFFu + ((u >> 16) & 1u);   // RNE
    return (unsigned short)(u >> 16);
}
static __device__ __forceinline__ float bf2f(unsigned short u) {
    return __builtin_bit_cast(float, (unsigned int)u << 16);
}
static __device__ __forceinline__ void glds16(const void* g, void* l) {
    __builtin_amdgcn_global_load_lds(
        (const __attribute__((address_space(1))) void*)g,
        (__attribute__((address_space(3))) void*)l, 16, 0, 0);
}

// ---------------------------------------------------------------------------
// Pre-pass kernels: one-time fp32 -> bf16 conversion into swizzled layouts.
// ---------------------------------------------------------------------------
__global__ __launch_bounds__(256)
void prep_q(const float* __restrict__ Q, unsigned short* __restrict__ Qbf)
{
    int i4 = blockIdx.x * 256 + threadIdx.x;      // 262144 float4s
    const float4 v = reinterpret_cast<const float4*>(Q)[i4];
    ushort4 o;
    o.x = f2bf(v.x); o.y = f2bf(v.y); o.z = f2bf(v.z); o.w = f2bf(v.w);
    reinterpret_cast<ushort4*>(Qbf)[i4] = o;
}

// Kswz tile j, 16B chunk (r, slot): holds K[j*64+r][(slot^(r&15))*8 .. +8]
__global__ __launch_bounds__(256)
void prep_k(const float* __restrict__ K, unsigned short* __restrict__ Kswz)
{
    int c = blockIdx.x * 256 + threadIdx.x;       // 131072 chunks
    int t = c >> 10;
    int r = (c >> 4) & 63;
    int slot = c & 15;
    int d0 = (slot ^ (r & 15)) << 3;
    const float* src = K + ((size_t)t * 64 + r) * D_DIM + d0;
    float4 a = *reinterpret_cast<const float4*>(src);
    float4 b = *reinterpret_cast<const float4*>(src + 4);
    bf16x8 o;
    o[0] = (short)f2bf(a.x); o[1] = (short)f2bf(a.y);
    o[2] = (short)f2bf(a.z); o[3] = (short)f2bf(a.w);
    o[4] = (short)f2bf(b.x); o[5] = (short)f2bf(b.y);
    o[6] = (short)f2bf(b.z); o[7] = (short)f2bf(b.w);
    *reinterpret_cast<bf16x8*>(&Kswz[(size_t)c * 8]) = o;
}

// Vtswz tile j, row d (128B = 8 slots): slot holds V[j*64+(slot^(d&7))*8 + i][d]
__global__ __launch_bounds__(256)
void prep_v(const float* __restrict__ V, unsigned short* __restrict__ Vt)
{
    __shared__ float sv[64 * 130];
    int t = blockIdx.x;                           // 128 tiles
    #pragma unroll
    for (int it = 0; it < 8; ++it) {
        int f4 = it * 256 + threadIdx.x;          // 2048 float4s
        int r  = f4 >> 5;
        int c4 = (f4 & 31) << 2;
        float4 v = *reinterpret_cast<const float4*>(V + ((size_t)t * 64 + r) * D_DIM + c4);
        sv[r * 130 + c4 + 0] = v.x;
        sv[r * 130 + c4 + 1] = v.y;
        sv[r * 130 + c4 + 2] = v.z;
        sv[r * 130 + c4 + 3] = v.w;
    }
    __syncthreads();
    #pragma unroll
    for (int ii = 0; ii < 4; ++ii) {
        int c = threadIdx.x * 4 + ii;             // 1024 chunks/tile
        int d = c >> 3;
        int slot = c & 7;
        int k0 = (slot ^ (d & 7)) << 3;
        bf16x8 o;
        #pragma unroll
        for (int i = 0; i < 8; ++i) o[i] = (short)f2bf(sv[(k0 + i) * 130 + d]);
        *reinterpret_cast<bf16x8*>(&Vt[(size_t)t * 8192 + c * 8]) = o;
    }
}

// ---------------------------------------------------------------------------
// Main flash kernel: bf16 pre-swizzled inputs, global_load_lds double-buffered
// 2-phase pipeline. One block = (kv-split, q-tile). 4 waves x 16 q-rows.
// ---------------------------------------------------------------------------
__global__ __launch_bounds__(256, 2)
void attn_pre(const unsigned short* __restrict__ Qbf,
              const unsigned short* __restrict__ Kswz,
              const unsigned short* __restrict__ Vtswz,
              float* __restrict__ Og,
              unsigned short* __restrict__ Opart,
              float* __restrict__ mpart, float* __restrict__ lpart)
{
    __shared__ char sbuf[2][2 * TILEB];           // [dbuf][ K | V ]
    __shared__ unsigned short sP[4 * 16 * 72];    // per-wave P relayout

    const int nsplit = (int)gridDim.x;
    const int split  = (int)blockIdx.x;
    const int qt     = (int)gridDim.y - 1 - (int)blockIdx.y;  // longest first
    const int tid    = threadIdx.x;
    const int w      = tid >> 6;
    const int lane   = tid & 63;
    const int g      = lane >> 4;
    const int lr     = lane & 15;

    const int qrow_base  = qt * QBLK + w * 16 + g * 4;
    const int q_frag_row = qt * QBLK + w * 16 + lr;

    bf16x8 qa[4];
    #pragma unroll
    for (int dc = 0; dc < 4; ++dc)
        qa[dc] = *reinterpret_cast<const bf16x8*>(
            Qbf + (size_t)q_frag_row * D_DIM + dc * 32 + g * 8);

    f32x4 acc[8];
    #pragma unroll
    for (int dj = 0; dj < 8; ++dj) acc[dj] = f32x4{0.f, 0.f, 0.f, 0.f};
    float m_run[4], l_run[4];
    #pragma unroll
    for (int r = 0; r < 4; ++r) { m_run[r] = -INFINITY; l_run[r] = 0.0f; }

    const float scale = 0.08838834764831845f;     // 1/sqrt(128)
    const int jtiles = qt + 1;
    unsigned short* sPw = sP + w * (16 * 72);

    auto STAGE = [&](int c, int j) {
        const char* gK = (const char*)Kswz + (size_t)j * TILEB;
        const char* gV = (const char*)Vtswz + (size_t)j * TILEB;
        char* lK = sbuf[c];
        char* lV = sbuf[c] + TILEB;
        #pragma unroll
        for (int it = 0; it < 4; ++it) {
            int goff = (it * 256 + tid) * 16;
            int loff = (it * 256 + (w << 6)) * 16;   // wave-uniform base
            glds16(gK + goff, lK + loff);
            glds16(gV + goff, lV + loff);
        }
    };

    int j = split, c = 0;
    if (j < jtiles) {
        STAGE(0, j);
        __syncthreads();
        for (; j < jtiles; j += nsplit) {
            int jn = j + nsplit;
            if (jn < jtiles) STAGE(c ^ 1, jn);

            const char* sKc = sbuf[c];
            const char* sVc = sbuf[c] + TILEB;

            // ---- QK^T ----
            f32x4 sf[4];
            __builtin_amdgcn_s_setprio(1);
            #pragma unroll
            for (int kj = 0; kj < 4; ++kj) {
                f32x4 accs = f32x4{0.f, 0.f, 0.f, 0.f};
                #pragma unroll
                for (int dc = 0; dc < 4; ++dc) {
                    int rowk = kj * 16 + lr;
                    int slot = (dc * 4 + g) ^ lr;
                    bf16x8 b = *reinterpret_cast<const bf16x8*>(
                        sKc + ((rowk << 8) | (slot << 4)));
                    accs = __builtin_amdgcn_mfma_f32_16x16x32_bf16(qa[dc], b, accs, 0, 0, 0);
                }
                sf[kj] = accs;
            }
            __builtin_amdgcn_s_setprio(0);

            // ---- scale + causal mask ----
            #pragma unroll
            for (int kj = 0; kj < 4; ++kj)
                #pragma unroll
                for (int r = 0; r < 4; ++r)
                    sf[kj][r] *= scale;
            if (j == qt) {
                #pragma unroll
                for (int kj = 0; kj < 4; ++kj) {
                    int kglob = j * KVBLK + kj * 16 + lr;
                    #pragma unroll
                    for (int r = 0; r < 4; ++r)
                        if (kglob > qrow_base + r) sf[kj][r] = -INFINITY;
                }
            }

            // ---- online softmax (16-lane row reduce) ----
            float tmax[4];
            #pragma unroll
            for (int r = 0; r < 4; ++r)
                tmax[r] = fmaxf(fmaxf(sf[0][r], sf[1][r]), fmaxf(sf[2][r], sf[3][r]));
            #pragma unroll
            for (int off = 1; off < 16; off <<= 1)
                #pragma unroll
                for (int r = 0; r < 4; ++r)
                    tmax[r] = fmaxf(tmax[r], __shfl_xor(tmax[r], off));

            float fsc[4], lt[4];
            #pragma unroll
            for (int r = 0; r < 4; ++r) {
                float mn = fmaxf(m_run[r], tmax[r]);
                fsc[r] = __expf(m_run[r] - mn);
                m_run[r] = mn;
                lt[r] = 0.0f;
            }
            #pragma unroll
            for (int kj = 0; kj < 4; ++kj)
                #pragma unroll
                for (int r = 0; r < 4; ++r) {
                    float p = __expf(sf[kj][r] - m_run[r]);
                    sf[kj][r] = p;
                    lt[r] += p;
                }
            #pragma unroll
            for (int off = 1; off < 16; off <<= 1)
                #pragma unroll
                for (int r = 0; r < 4; ++r)
                    lt[r] += __shfl_xor(lt[r], off);
            #pragma unroll
            for (int r = 0; r < 4; ++r)
                l_run[r] = l_run[r] * fsc[r] + lt[r];
            #pragma unroll
            for (int dj = 0; dj < 8; ++dj)
                #pragma unroll
                for (int r = 0; r < 4; ++r)
                    acc[dj][r] *= fsc[r];

            // ---- P: C-layout -> LDS -> A-layout ----
            #pragma unroll
            for (int kj = 0; kj < 4; ++kj)
                #pragma unroll
                for (int r = 0; r < 4; ++r)
                    sPw[(g * 4 + r) * 72 + kj * 16 + lr] = f2bf(sf[kj][r]);
            bf16x8 pa[2];
            #pragma unroll
            for (int kc = 0; kc < 2; ++kc)
                pa[kc] = *reinterpret_cast<bf16x8*>(sPw + lr * 72 + kc * 32 + g * 8);

            // ---- PV ----
            __builtin_amdgcn_s_setprio(1);
            #pragma unroll
            for (int dj = 0; dj < 8; ++dj) {
                #pragma unroll
                for (int kc = 0; kc < 2; ++kc) {
                    int d = dj * 16 + lr;
                    int slot = (kc * 4 + g) ^ (lr & 7);
                    bf16x8 b = *reinterpret_cast<const bf16x8*>(
                        sVc + ((d << 7) | (slot << 4)));
                    acc[dj] = __builtin_amdgcn_mfma_f32_16x16x32_bf16(pa[kc], b, acc[dj], 0, 0, 0);
                }
            }
            __builtin_amdgcn_s_setprio(0);

            __syncthreads();
            c ^= 1;
        }
    }

    // ---- epilogue ----
    if (nsplit == 1) {
        #pragma unroll
        for (int r = 0; r < 4; ++r) {
            float inv = 1.0f / l_run[r];
            int row = qrow_base + r;
            #pragma unroll
            for (int dj = 0; dj < 8; ++dj)
                Og[row * D_DIM + dj * 16 + lr] = acc[dj][r] * inv;
        }
    } else {
        int pidx = qt * nsplit + split;
        unsigned short* Ob = Opart + (size_t)pidx * (QBLK * D_DIM);
        #pragma unroll
        for (int r = 0; r < 4; ++r) {
            int row = w * 16 + g * 4 + r;
            #pragma unroll
            for (int dj = 0; dj < 8; ++dj)
                Ob[row * D_DIM + dj * 16 + lr] = f2bf(acc[dj][r]);
        }
        if (lr == 0) {
            #pragma unroll
            for (int r = 0; r < 4; ++r) {
                mpart[pidx * QBLK + w * 16 + g * 4 + r] = m_run[r];
                lpart[pidx * QBLK + w * 16 + g * 4 + r] = l_run[r];
            }
        }
    }
}

// ---------------------------------------------------------------------------
// merge: combine nsplit bf16 partials per q-tile.
// ---------------------------------------------------------------------------
__global__ __launch_bounds__(256)
void attn_merge(const unsigned short* __restrict__ Opart,
                const float* __restrict__ mpart, const float* __restrict__ lpart,
                float* __restrict__ Og, int nsplit)
{
    int qt  = blockIdx.x;
    int tid = threadIdx.x;
    int r   = tid >> 2;          // 0..63
    int c0  = (tid & 3) * 32;

    float M = -INFINITY;
    for (int s = 0; s < nsplit; ++s)
        M = fmaxf(M, mpart[(qt * nsplit + s) * QBLK + r]);
    float e[8];
    float L = 0.0f;
    for (int s = 0; s < nsplit; ++s) {
        e[s] = __expf(mpart[(qt * nsplit + s) * QBLK + r] - M);
        L += e[s] * lpart[(qt * nsplit + s) * QBLK + r];
    }
    float invL = 1.0f / L;

    for (int c8 = 0; c8 < 4; ++c8) {
        float a[8] = {0.f, 0.f, 0.f, 0.f, 0.f, 0.f, 0.f, 0.f};
        for (int s = 0; s < nsplit; ++s) {
            bf16x8 o = *reinterpret_cast<const bf16x8*>(
                &Opart[((size_t)(qt * nsplit + s) * QBLK + r) * D_DIM + c0 + c8 * 8]);
            #pragma unroll
            for (int i = 0; i < 8; ++i)
                a[i] += e[s] * bf2f((unsigned short)o[i]);
        }
        float4 w0 = {a[0] * invL, a[1] * invL, a[2] * invL, a[3] * invL};
        float4 w1 = {a[4] * invL, a[5] * invL, a[6] * invL, a[7] * invL};
        float* dst = Og + ((size_t)qt * QBLK + r) * D_DIM + c0 + c8 * 8;
        *reinterpret_cast<float4*>(dst) = w0;
        *reinterpret_cast<float4*>(dst + 4) = w1;
    }
}

// ---------------------------------------------------------------------------
// Fallback (ws too small for bf16 buffers): round-1 fp32-staging kernel,
// nsplit=1, writes d_out directly.
// ---------------------------------------------------------------------------
__global__ __launch_bounds__(256, 2)
void attn_f32(const float* __restrict__ Qg, const float* __restrict__ Kg,
              const float* __restrict__ Vg, float* __restrict__ Og)
{
    __shared__ unsigned short sK [KVBLK * 128];
    __shared__ unsigned short sVt[128 * KVBLK];
    __shared__ unsigned short sP [4 * 16 * 72];

    const int qt   = (int)gridDim.y - 1 - (int)blockIdx.y;
    const int tid  = threadIdx.x;
    const int w    = tid >> 6;
    const int lane = tid & 63;
    const int g    = lane >> 4;
    const int lr   = lane & 15;

    const int qrow_base  = qt * QBLK + w * 16 + g * 4;
    const int q_frag_row = qt * QBLK + w * 16 + lr;

    bf16x8 qa[4];
    #pragma unroll
    for (int dc = 0; dc < 4; ++dc) {
        const float* src = Qg + q_frag_row * D_DIM + dc * 32 + g * 8;
        bf16x8 v;
        #pragma unroll
        for (int i = 0; i < 8; ++i) v[i] = (short)f2bf(src[i]);
        qa[dc] = v;
    }

    f32x4 acc[8];
    #pragma unroll
    for (int dj = 0; dj < 8; ++dj) acc[dj] = f32x4{0.f, 0.f, 0.f, 0.f};
    float m_run[4], l_run[4];
    #pragma unroll
    for (int r = 0; r < 4; ++r) { m_run[r] = -INFINITY; l_run[r] = 0.0f; }

    const float scale = 0.08838834764831845f;
    const int jtiles = qt + 1;
    unsigned short* sPw = sP + w * (16 * 72);
    char* sKc = reinterpret_cast<char*>(sK);
    char* sVc = reinterpret_cast<char*>(sVt);

    for (int j = 0; j < jtiles; ++j) {
        __syncthreads();
        #pragma unroll
        for (int it = 0; it < 8; ++it) {
            int flat4 = it * 256 + tid;
            int r  = flat4 >> 5;
            int d0 = (flat4 & 31) << 2;
            const float4 kv = *reinterpret_cast<const float4*>(
                Kg + (j * KVBLK + r) * D_DIM + d0);
            ushort4 wv;
            wv.x = f2bf(kv.x); wv.y = f2bf(kv.y); wv.z = f2bf(kv.z); wv.w = f2bf(kv.w);
            int byte = (r << 8) | (((d0 >> 3) ^ (r & 15)) << 4) | ((d0 & 7) << 1);
            *reinterpret_cast<ushort4*>(sKc + byte) = wv;
        }
        {
            int d = tid & 127;
            int khalf = tid >> 7;
            #pragma unroll
            for (int it = 0; it < 8; ++it) {
                int k0 = it * 8 + khalf * 4;
                const float* vsrc = Vg + (j * KVBLK + k0) * D_DIM + d;
                ushort4 wv;
                wv.x = f2bf(vsrc[0 * D_DIM]); wv.y = f2bf(vsrc[1 * D_DIM]);
                wv.z = f2bf(vsrc[2 * D_DIM]); wv.w = f2bf(vsrc[3 * D_DIM]);
                int byte = (d << 7) | (((k0 >> 3) ^ (d & 7)) << 4) | ((k0 & 7) << 1);
                *reinterpret_cast<ushort4*>(sVc + byte) = wv;
            }
        }
        __syncthreads();

        f32x4 sf[4];
        #pragma unroll
        for (int kj = 0; kj < 4; ++kj) {
            f32x4 accs = f32x4{0.f, 0.f, 0.f, 0.f};
            #pragma unroll
            for (int dc = 0; dc < 4; ++dc) {
                int rowk = kj * 16 + lr;
                int slot = (dc * 4 + g) ^ lr;
                bf16x8 b = *reinterpret_cast<bf16x8*>(sKc + ((rowk << 8) | (slot << 4)));
                accs = __builtin_amdgcn_mfma_f32_16x16x32_bf16(qa[dc], b, accs, 0, 0, 0);
            }
            sf[kj] = accs;
        }
        #pragma unroll
        for (int kj = 0; kj < 4; ++kj)
            #pragma unroll
            for (int r = 0; r < 4; ++r)
                sf[kj][r] *= scale;
        if (j == qt) {
            #pragma unroll
            for (int kj = 0; kj < 4; ++kj) {
                int kglob = j * KVBLK + kj * 16 + lr;
                #pragma unroll
                for (int r = 0; r < 4; ++r)
                    if (kglob > qrow_base + r) sf[kj][r] = -INFINITY;
            }
        }
        float tmax[4];
        #pragma unroll
        for (int r = 0; r < 4; ++r)
            tmax[r] = fmaxf(fmaxf(sf[0][r], sf[1][r]), fmaxf(sf[2][r], sf[3][r]));
        #pragma unroll
        for (int off = 1; off < 16; off <<= 1)
            #pragma unroll
            for (int r = 0; r < 4; ++r)
                tmax[r] = fmaxf(tmax[r], __shfl_xor(tmax[r], off));
        float fsc[4], lt[4];
        #pragma unroll
        for (int r = 0; r < 4; ++r) {
            float mn = fmaxf(m_run[r], tmax[r]);
            fsc[r] = __expf(m_run[r] - mn);
            m_run[r] = mn;
            lt[r] = 0.0f;
        }
        #pragma unroll
        for (int kj = 0; kj < 4; ++kj)
            #pragma unroll
            for (int r = 0; r < 4; ++r) {
                float p = __expf(sf[kj][r] - m_run[r]);
                sf[kj][r] = p;
                lt[r] += p;
            }
        #pragma unroll
        for (int off = 1; off < 16; off <<= 1)
            #pragma unroll
            for (int r = 0; r < 4; ++r)
                lt[r] += __shfl_xor(lt[r], off);
        #pragma unroll
        for (int r = 0; r < 4; ++r)
            l_run[r] = l_run[r] * fsc[r] + lt[r];
        #pragma unroll
        for (int dj = 0; dj < 8; ++dj)
            #pragma unroll
            for (int r = 0; r < 4; ++r)
                acc[dj][r] *= fsc[r];
        #pragma unroll
        for (int kj = 0; kj < 4; ++kj)
            #pragma unroll
            for (int r = 0; r < 4; ++r)
                sPw[(g * 4 + r) * 72 + kj * 16 + lr] = f2bf(sf[kj][r]);
        bf16x8 pa[2];
        #pragma unroll
        for (int kc = 0; kc < 2; ++kc)
            pa[kc] = *reinterpret_cast<bf16x8*>(sPw + lr * 72 + kc * 32 + g * 8);
        #pragma unroll
        for (int dj = 0; dj < 8; ++dj) {
            #pragma unroll
            for (int kc = 0; kc < 2; ++kc) {
                int d = dj * 16 + lr;
                int slot = (kc * 4 + g) ^ (lr & 7);
                bf16x8 b = *reinterpret_cast<bf16x8*>(sVc + ((d << 7) | (slot << 4)));
                acc[dj] = __builtin_amdgcn_mfma_f32_16x16x32_bf16(pa[kc], b, acc[dj], 0, 0, 0);
            }
        }
    }
    #pragma unroll
    for (int r = 0; r < 4; ++r) {
        float inv = 1.0f / l_run[r];
        int row = qrow_base + r;
        #pragma unroll
        for (int dj = 0; dj < 8; ++dj)
            Og[row * D_DIM + dj * 16 + lr] = acc[dj][r] * inv;
    }
}

// ---------------------------------------------------------------------------
extern "C" void kernel_launch(void* const* d_in, const int* in_sizes, int n_in,
                              void* d_out, int out_size, void* d_ws, size_t ws_size,
                              hipStream_t stream)
{
    const float* Qg = (const float*)d_in[0];
    const float* Kg = (const float*)d_in[1];
    const float* Vg = (const float*)d_in[2];
    float* Og = (float*)d_out;

    const size_t bfElems = (size_t)S_TOTAL * D_DIM;       // per-tensor bf16 elems
    auto need = [bfElems](int n) -> size_t {
        size_t base = 3 * bfElems * 2;                    // Qbf,Kswz,Vtswz bytes
        if (n > 1)
            base += (size_t)n * QTILES * ((size_t)QBLK * D_DIM * 2 + QBLK * 8);
        return base;
    };

    if (d_ws == nullptr || ws_size < need(1)) {
        hipLaunchKernelGGL(attn_f32, dim3(1, QTILES), dim3(256), 0, stream,
                           Qg, Kg, Vg, Og);
        return;
    }

    int nsplit = 8;
    while (nsplit > 1 && ws_size < need(nsplit)) nsplit >>= 1;

    unsigned short* Qbf  = (unsigned short*)d_ws;
    unsigned short* Kswz = Qbf + bfElems;
    unsigned short* Vt   = Kswz + bfElems;
    unsigned short* Opart = Vt + bfElems;
    float* mpart = (float*)(Opart + (size_t)nsplit * QTILES * QBLK * D_DIM);
    float* lpart = mpart + (size_t)nsplit * QTILES * QBLK;

    hipLaunchKernelGGL(prep_q, dim3(1024), dim3(256), 0, stream, Qg, Qbf);
    hipLaunchKernelGGL(prep_k, dim3(512),  dim3(256), 0, stream, Kg, Kswz);
    hipLaunchKernelGGL(prep_v, dim3(128),  dim3(256), 0, stream, Vg, Vt);

    hipLaunchKernelGGL(attn_pre, dim3(nsplit, QTILES), dim3(256), 0, stream,
                       Qbf, Kswz, Vt, Og, Opart, mpart, lpart);
    if (nsplit > 1)
        hipLaunchKernelGGL(attn_merge, dim3(QTILES), dim3(256), 0, stream,
                           Opart, mpart, lpart, Og, nsplit);
}

// Round 3
// 60.115 us; speedup vs baseline: 1.7138x; 1.2656x over previous
//
#include <hip/hip_runtime.h>

#define S_TOTAL 8192
#define D_DIM   128
#define QBLK    128            // 4 waves x 32 q-rows
#define KVBLK   64
#define QT64    64             // q-tiles of 128 rows
#define TILEB   16384          // one bf16 K or V tile in bytes (64*128*2)
#define QSCALE  0.12751879523178264f   // (1/sqrt(128)) * log2(e)
#define NEG_BIG -1.0e30f
#define THR     8.0f

typedef __attribute__((ext_vector_type(8)))  short    bf16x8;
typedef __attribute__((ext_vector_type(16))) float    f32x16;
typedef __attribute__((ext_vector_type(4)))  unsigned u32x4;

static __device__ __forceinline__ unsigned short f2bf(float f) {
    unsigned int u = __builtin_bit_cast(unsigned int, f);
    u += 0x7FFFu + ((u >> 16) & 1u);   // RNE
    return (unsigned short)(u >> 16);
}
static __device__ __forceinline__ float bf2f(unsigned short u) {
    return __builtin_bit_cast(float, (unsigned int)u << 16);
}
static __device__ __forceinline__ void glds16(const void* g, void* l) {
    __builtin_amdgcn_global_load_lds(
        (const __attribute__((address_space(1))) void*)g,
        (__attribute__((address_space(3))) void*)l, 16, 0, 0);
}
static __device__ __forceinline__ unsigned pk2(float lo, float hi) {
    unsigned r;
    asm("v_cvt_pk_bf16_f32 %0, %1, %2" : "=v"(r) : "v"(lo), "v"(hi));
    return r;
}
static __device__ __forceinline__ void pl32swap(unsigned& x, unsigned& y) {
    asm("v_permlane32_swap_b32 %0, %1" : "+v"(x), "+v"(y));
}

// ---------------------------------------------------------------------------
// Pre-pass kernels
// ---------------------------------------------------------------------------
__global__ __launch_bounds__(256)
void prep_q(const float* __restrict__ Q, unsigned short* __restrict__ Qbf)
{
    int i4 = blockIdx.x * 256 + threadIdx.x;      // 262144 float4s
    const float4 v = reinterpret_cast<const float4*>(Q)[i4];
    ushort4 o;
    o.x = f2bf(v.x * QSCALE); o.y = f2bf(v.y * QSCALE);
    o.z = f2bf(v.z * QSCALE); o.w = f2bf(v.w * QSCALE);
    reinterpret_cast<ushort4*>(Qbf)[i4] = o;
}

// Kswz tile j, 16B chunk (r, slot): holds K[j*64+r][(slot^(r&15))*8 .. +8]
__global__ __launch_bounds__(256)
void prep_k(const float* __restrict__ K, unsigned short* __restrict__ Kswz)
{
    int c = blockIdx.x * 256 + threadIdx.x;       // 131072 chunks
    int t = c >> 10;
    int r = (c >> 4) & 63;
    int slot = c & 15;
    int d0 = (slot ^ (r & 15)) << 3;
    const float* src = K + ((size_t)t * 64 + r) * D_DIM + d0;
    float4 a = *reinterpret_cast<const float4*>(src);
    float4 b = *reinterpret_cast<const float4*>(src + 4);
    bf16x8 o;
    o[0] = (short)f2bf(a.x); o[1] = (short)f2bf(a.y);
    o[2] = (short)f2bf(a.z); o[3] = (short)f2bf(a.w);
    o[4] = (short)f2bf(b.x); o[5] = (short)f2bf(b.y);
    o[6] = (short)f2bf(b.z); o[7] = (short)f2bf(b.w);
    *reinterpret_cast<bf16x8*>(&Kswz[(size_t)c * 8]) = o;
}

// Vtswz tile j, row d (8 slots of 16B): slot holds V[j*64+(slot^(d&7))*8 + i][d]
// 2 blocks per tile (d-halves) for parallelism.
__global__ __launch_bounds__(256)
void prep_v(const float* __restrict__ V, unsigned short* __restrict__ Vt)
{
    __shared__ float sv[64 * 68];
    int t = blockIdx.x >> 1;
    int h = blockIdx.x & 1;
    #pragma unroll
    for (int it = 0; it < 4; ++it) {
        int f4 = it * 256 + threadIdx.x;          // 1024 float4s (64k x 64d)
        int r   = f4 >> 4;
        int c16 = (f4 & 15) << 2;
        float4 v = *reinterpret_cast<const float4*>(
            V + ((size_t)t * 64 + r) * D_DIM + h * 64 + c16);
        sv[r * 68 + c16 + 0] = v.x;
        sv[r * 68 + c16 + 1] = v.y;
        sv[r * 68 + c16 + 2] = v.z;
        sv[r * 68 + c16 + 3] = v.w;
    }
    __syncthreads();
    #pragma unroll
    for (int ii = 0; ii < 2; ++ii) {
        int cl = threadIdx.x * 2 + ii;            // 512 chunks per block
        int dl = cl >> 3;
        int slot = cl & 7;
        int d = h * 64 + dl;
        int k0 = (slot ^ (d & 7)) << 3;
        bf16x8 o;
        #pragma unroll
        for (int i = 0; i < 8; ++i) o[i] = (short)f2bf(sv[(k0 + i) * 68 + dl]);
        *reinterpret_cast<bf16x8*>(&Vt[(size_t)t * 8192 + ((size_t)(d * 8 + slot)) * 8]) = o;
    }
}

// ---------------------------------------------------------------------------
// Main kernel: 32x32 swapped-QK^T flash attention.
// Block = (kv-split, q-tile of 128 rows). 4 waves x 32 q-rows.
// ---------------------------------------------------------------------------
__global__ __launch_bounds__(256, 2)
void attn32(const unsigned short* __restrict__ Qbf,
            const unsigned short* __restrict__ Kswz,
            const unsigned short* __restrict__ Vtswz,
            float* __restrict__ Og,
            unsigned short* __restrict__ Opart,
            float* __restrict__ mpart, float* __restrict__ lpart)
{
    __shared__ char sbuf[2][2 * TILEB];           // [dbuf][ K | V ] = 64 KB

    const int nsplit = (int)gridDim.x;
    const int split  = (int)blockIdx.x;
    const int qt     = (int)gridDim.y - 1 - (int)blockIdx.y;  // longest first
    const int tid    = threadIdx.x;
    const int w      = tid >> 6;
    const int lane   = tid & 63;
    const int qc     = lane & 31;                 // q column within wave tile
    const int hi     = lane >> 5;

    const int qw_base = qt * QBLK + w * 32;
    const int qglob   = qw_base + qc;

    // Q as B-fragments: lane holds col=q, d-window = dc*16 + hi*8
    bf16x8 qf[8];
    #pragma unroll
    for (int dc = 0; dc < 8; ++dc)
        qf[dc] = *reinterpret_cast<const bf16x8*>(
            Qbf + (size_t)qglob * D_DIM + dc * 16 + hi * 8);

    f32x16 acc[4];
    #pragma unroll
    for (int dt = 0; dt < 4; ++dt)
        #pragma unroll
        for (int r = 0; r < 16; ++r) acc[dt][r] = 0.0f;
    float m_run = NEG_BIG, l_run = 0.0f;

    const int jtiles = 2 * qt + 2;

    auto STAGE = [&](int c, int j) {
        const char* gK = (const char*)Kswz + (size_t)j * TILEB;
        const char* gV = (const char*)Vtswz + (size_t)j * TILEB;
        char* lK = sbuf[c];
        char* lV = sbuf[c] + TILEB;
        #pragma unroll
        for (int it = 0; it < 4; ++it) {
            int goff = (it * 256 + tid) * 16;
            int loff = (it * 256 + (w << 6)) * 16;   // wave-uniform base
            glds16(gK + goff, lK + loff);
            glds16(gV + goff, lV + loff);
        }
    };

    int j = split, c = 0;
    if (j < jtiles) {
        STAGE(0, j);
        __syncthreads();
        for (; j < jtiles; j += nsplit) {
            int jn = j + nsplit;
            if (jn < jtiles) STAGE(c ^ 1, jn);

            const char* bK = sbuf[c];
            const char* bV = sbuf[c] + TILEB;

            // ---- QK^T (swapped): S^T[k][q], col=q=lane&31 ----
            f32x16 sc[2];
            __builtin_amdgcn_s_setprio(1);
            #pragma unroll
            for (int kj = 0; kj < 2; ++kj) {
                f32x16 a;
                #pragma unroll
                for (int r = 0; r < 16; ++r) a[r] = 0.0f;
                int rK = kj * 32 + qc;
                #pragma unroll
                for (int dc = 0; dc < 8; ++dc) {
                    int slot = ((dc << 1) | hi) ^ (rK & 15);
                    bf16x8 kf = *reinterpret_cast<const bf16x8*>(
                        bK + (rK << 8) + (slot << 4));
                    a = __builtin_amdgcn_mfma_f32_32x32x16_bf16(kf, qf[dc], a, 0, 0, 0);
                }
                sc[kj] = a;
            }
            __builtin_amdgcn_s_setprio(0);

            // ---- causal mask (scores already scaled+log2e via Q prep) ----
            if (j * 64 + 63 > qw_base) {
                #pragma unroll
                for (int kj = 0; kj < 2; ++kj)
                    #pragma unroll
                    for (int r = 0; r < 16; ++r) {
                        int kg = j * 64 + kj * 32 + (r & 3) + 8 * (r >> 2) + 4 * hi;
                        if (kg > qglob) sc[kj][r] = -INFINITY;
                    }
            }

            // ---- online softmax: in-lane max over 32, then lane-pair swap ----
            float mx = sc[0][0];
            #pragma unroll
            for (int r = 1; r < 16; ++r) mx = fmaxf(mx, sc[0][r]);
            #pragma unroll
            for (int r = 0; r < 16; ++r) mx = fmaxf(mx, sc[1][r]);
            float tmax = fmaxf(mx, __shfl_xor(mx, 32));

            if (__any(tmax > m_run + THR)) {
                float mnew = fmaxf(m_run, tmax);
                float fsc = __builtin_amdgcn_exp2f(m_run - mnew);
                m_run = mnew;
                l_run *= fsc;
                #pragma unroll
                for (int dt = 0; dt < 4; ++dt)
                    #pragma unroll
                    for (int r = 0; r < 16; ++r) acc[dt][r] *= fsc;
            }

            float lt = 0.0f;
            #pragma unroll
            for (int kj = 0; kj < 2; ++kj)
                #pragma unroll
                for (int r = 0; r < 16; ++r) {
                    float p = __builtin_amdgcn_exp2f(sc[kj][r] - m_run);
                    sc[kj][r] = p;
                    lt += p;
                }
            lt += __shfl_xor(lt, 32);
            l_run += lt;

            // ---- PV: O^T[d][q] += V^T . P, P-frags via cvt_pk + permlane ----
            #pragma unroll
            for (int ck = 0; ck < 4; ++ck) {
                const int kjx = ck >> 1;
                const int rb  = (ck & 1) * 8;
                unsigned a = pk2(sc[kjx][rb + 0], sc[kjx][rb + 1]);
                unsigned b = pk2(sc[kjx][rb + 4], sc[kjx][rb + 5]);
                unsigned cc = pk2(sc[kjx][rb + 2], sc[kjx][rb + 3]);
                unsigned d = pk2(sc[kjx][rb + 6], sc[kjx][rb + 7]);
                pl32swap(a, b);    // dst-high <-> src-low
                pl32swap(cc, d);
                u32x4 t = {a, cc, b, d};
                bf16x8 pf = __builtin_bit_cast(bf16x8, t);

                __builtin_amdgcn_s_setprio(1);
                #pragma unroll
                for (int dt = 0; dt < 4; ++dt) {
                    int dV = dt * 32 + qc;
                    int slot = ((ck << 1) | hi) ^ (dV & 7);
                    bf16x8 vf = *reinterpret_cast<const bf16x8*>(
                        bV + (dV << 7) + (slot << 4));
                    acc[dt] = __builtin_amdgcn_mfma_f32_32x32x16_bf16(vf, pf, acc[dt], 0, 0, 0);
                }
                __builtin_amdgcn_s_setprio(0);
            }

            __syncthreads();
            c ^= 1;
        }
    }

    // ---- epilogue ----
    if (nsplit == 1) {
        float invl = 1.0f / l_run;
        #pragma unroll
        for (int dt = 0; dt < 4; ++dt)
            #pragma unroll
            for (int r = 0; r < 16; ++r) {
                int d = dt * 32 + (r & 3) + 8 * (r >> 2) + 4 * hi;
                Og[(size_t)qglob * D_DIM + d] = acc[dt][r] * invl;
            }
    } else {
        // O^T -> LDS transpose -> coalesced bf16 partial stores
        unsigned short* sO = reinterpret_cast<unsigned short*>(
            &sbuf[0][0]) + w * (32 * 136 + 16);   // 8736 B region per wave
        #pragma unroll
        for (int dt = 0; dt < 4; ++dt)
            #pragma unroll
            for (int i = 0; i < 8; ++i) {
                unsigned pk = pk2(acc[dt][2 * i], acc[dt][2 * i + 1]);
                int d = dt * 32 + (i & 1) * 2 + (i >> 1) * 8 + 4 * hi;
                *reinterpret_cast<unsigned*>(&sO[qc * 136 + d]) = pk;
            }
        const int sidx = split;
        #pragma unroll
        for (int it = 0; it < 8; ++it) {
            int flat = it * 64 + lane;            // 512 ushort8 per wave
            int q  = flat >> 4;
            int s8 = flat & 15;
            bf16x8 v = *reinterpret_cast<const bf16x8*>(&sO[q * 136 + s8 * 8]);
            *reinterpret_cast<bf16x8*>(
                Opart + ((size_t)sidx * S_TOTAL + qw_base + q) * D_DIM + s8 * 8) = v;
        }
        if (hi == 0) {
            mpart[(size_t)sidx * S_TOTAL + qglob] = m_run;
            lpart[(size_t)sidx * S_TOTAL + qglob] = l_run;
        }
    }
}

// ---------------------------------------------------------------------------
// merge: combine nsplit partials per q-row (log2-domain m).
// ---------------------------------------------------------------------------
__global__ __launch_bounds__(256)
void attn_merge2(const unsigned short* __restrict__ Opart,
                 const float* __restrict__ mpart, const float* __restrict__ lpart,
                 float* __restrict__ Og, int nsplit)
{
    int tid = threadIdx.x;
    int row = blockIdx.x * 16 + (tid >> 4);
    int c8  = tid & 15;

    float M = NEG_BIG;
    for (int s = 0; s < nsplit; ++s)
        M = fmaxf(M, mpart[(size_t)s * S_TOTAL + row]);
    float L = 0.0f;
    for (int s = 0; s < nsplit; ++s)
        L += __builtin_amdgcn_exp2f(mpart[(size_t)s * S_TOTAL + row] - M)
             * lpart[(size_t)s * S_TOTAL + row];
    float invL = 1.0f / L;

    float a[8] = {0.f, 0.f, 0.f, 0.f, 0.f, 0.f, 0.f, 0.f};
    for (int s = 0; s < nsplit; ++s) {
        float e = __builtin_amdgcn_exp2f(mpart[(size_t)s * S_TOTAL + row] - M);
        bf16x8 o = *reinterpret_cast<const bf16x8*>(
            &Opart[((size_t)s * S_TOTAL + row) * D_DIM + c8 * 8]);
        #pragma unroll
        for (int i = 0; i < 8; ++i)
            a[i] += e * bf2f((unsigned short)o[i]);
    }
    float4 w0 = {a[0] * invL, a[1] * invL, a[2] * invL, a[3] * invL};
    float4 w1 = {a[4] * invL, a[5] * invL, a[6] * invL, a[7] * invL};
    float* dst = Og + (size_t)row * D_DIM + c8 * 8;
    *reinterpret_cast<float4*>(dst)     = w0;
    *reinterpret_cast<float4*>(dst + 4) = w1;
}

// ---------------------------------------------------------------------------
// Fallback (no workspace): round-1 self-contained kernel. 64-row q-tiles.
// ---------------------------------------------------------------------------
typedef __attribute__((ext_vector_type(4))) float f32x4;

__global__ __launch_bounds__(256, 2)
void attn_f32(const float* __restrict__ Qg, const float* __restrict__ Kg,
              const float* __restrict__ Vg, float* __restrict__ Og)
{
    __shared__ unsigned short sK [64 * 128];
    __shared__ unsigned short sVt[128 * 64];
    __shared__ unsigned short sP [4 * 16 * 72];

    const int qt   = (int)gridDim.y - 1 - (int)blockIdx.y;
    const int tid  = threadIdx.x;
    const int w    = tid >> 6;
    const int lane = tid & 63;
    const int g    = lane >> 4;
    const int lr   = lane & 15;

    const int qrow_base  = qt * 64 + w * 16 + g * 4;
    const int q_frag_row = qt * 64 + w * 16 + lr;

    bf16x8 qa[4];
    #pragma unroll
    for (int dc = 0; dc < 4; ++dc) {
        const float* src = Qg + q_frag_row * D_DIM + dc * 32 + g * 8;
        bf16x8 v;
        #pragma unroll
        for (int i = 0; i < 8; ++i) v[i] = (short)f2bf(src[i]);
        qa[dc] = v;
    }

    f32x4 acc[8];
    #pragma unroll
    for (int dj = 0; dj < 8; ++dj) acc[dj] = f32x4{0.f, 0.f, 0.f, 0.f};
    float m_run[4], l_run[4];
    #pragma unroll
    for (int r = 0; r < 4; ++r) { m_run[r] = -INFINITY; l_run[r] = 0.0f; }

    const float scale = 0.08838834764831845f;
    const int jtiles = qt + 1;
    unsigned short* sPw = sP + w * (16 * 72);
    char* sKc = reinterpret_cast<char*>(sK);
    char* sVc = reinterpret_cast<char*>(sVt);

    for (int j = 0; j < jtiles; ++j) {
        __syncthreads();
        #pragma unroll
        for (int it = 0; it < 8; ++it) {
            int flat4 = it * 256 + tid;
            int r  = flat4 >> 5;
            int d0 = (flat4 & 31) << 2;
            const float4 kv = *reinterpret_cast<const float4*>(
                Kg + (j * 64 + r) * D_DIM + d0);
            ushort4 wv;
            wv.x = f2bf(kv.x); wv.y = f2bf(kv.y); wv.z = f2bf(kv.z); wv.w = f2bf(kv.w);
            int byte = (r << 8) | (((d0 >> 3) ^ (r & 15)) << 4) | ((d0 & 7) << 1);
            *reinterpret_cast<ushort4*>(sKc + byte) = wv;
        }
        {
            int d = tid & 127;
            int khalf = tid >> 7;
            #pragma unroll
            for (int it = 0; it < 8; ++it) {
                int k0 = it * 8 + khalf * 4;
                const float* vsrc = Vg + (j * 64 + k0) * D_DIM + d;
                ushort4 wv;
                wv.x = f2bf(vsrc[0 * D_DIM]); wv.y = f2bf(vsrc[1 * D_DIM]);
                wv.z = f2bf(vsrc[2 * D_DIM]); wv.w = f2bf(vsrc[3 * D_DIM]);
                int byte = (d << 7) | (((k0 >> 3) ^ (d & 7)) << 4) | ((k0 & 7) << 1);
                *reinterpret_cast<ushort4*>(sVc + byte) = wv;
            }
        }
        __syncthreads();

        f32x4 sf[4];
        #pragma unroll
        for (int kj = 0; kj < 4; ++kj) {
            f32x4 accs = f32x4{0.f, 0.f, 0.f, 0.f};
            #pragma unroll
            for (int dc = 0; dc < 4; ++dc) {
                int rowk = kj * 16 + lr;
                int slot = (dc * 4 + g) ^ lr;
                bf16x8 b = *reinterpret_cast<bf16x8*>(sKc + ((rowk << 8) | (slot << 4)));
                accs = __builtin_amdgcn_mfma_f32_16x16x32_bf16(qa[dc], b, accs, 0, 0, 0);
            }
            sf[kj] = accs;
        }
        #pragma unroll
        for (int kj = 0; kj < 4; ++kj)
            #pragma unroll
            for (int r = 0; r < 4; ++r)
                sf[kj][r] *= scale;
        if (j == qt) {
            #pragma unroll
            for (int kj = 0; kj < 4; ++kj) {
                int kglob = j * 64 + kj * 16 + lr;
                #pragma unroll
                for (int r = 0; r < 4; ++r)
                    if (kglob > qrow_base + r) sf[kj][r] = -INFINITY;
            }
        }
        float tmax[4];
        #pragma unroll
        for (int r = 0; r < 4; ++r)
            tmax[r] = fmaxf(fmaxf(sf[0][r], sf[1][r]), fmaxf(sf[2][r], sf[3][r]));
        #pragma unroll
        for (int off = 1; off < 16; off <<= 1)
            #pragma unroll
            for (int r = 0; r < 4; ++r)
                tmax[r] = fmaxf(tmax[r], __shfl_xor(tmax[r], off));
        float fsc[4], lt[4];
        #pragma unroll
        for (int r = 0; r < 4; ++r) {
            float mn = fmaxf(m_run[r], tmax[r]);
            fsc[r] = __expf(m_run[r] - mn);
            m_run[r] = mn;
            lt[r] = 0.0f;
        }
        #pragma unroll
        for (int kj = 0; kj < 4; ++kj)
            #pragma unroll
            for (int r = 0; r < 4; ++r) {
                float p = __expf(sf[kj][r] - m_run[r]);
                sf[kj][r] = p;
                lt[r] += p;
            }
        #pragma unroll
        for (int off = 1; off < 16; off <<= 1)
            #pragma unroll
            for (int r = 0; r < 4; ++r)
                lt[r] += __shfl_xor(lt[r], off);
        #pragma unroll
        for (int r = 0; r < 4; ++r)
            l_run[r] = l_run[r] * fsc[r] + lt[r];
        #pragma unroll
        for (int dj = 0; dj < 8; ++dj)
            #pragma unroll
            for (int r = 0; r < 4; ++r)
                acc[dj][r] *= fsc[r];
        #pragma unroll
        for (int kj = 0; kj < 4; ++kj)
            #pragma unroll
            for (int r = 0; r < 4; ++r)
                sPw[(g * 4 + r) * 72 + kj * 16 + lr] = f2bf(sf[kj][r]);
        bf16x8 pa[2];
        #pragma unroll
        for (int kc = 0; kc < 2; ++kc)
            pa[kc] = *reinterpret_cast<bf16x8*>(sPw + lr * 72 + kc * 32 + g * 8);
        #pragma unroll
        for (int dj = 0; dj < 8; ++dj) {
            #pragma unroll
            for (int kc = 0; kc < 2; ++kc) {
                int d = dj * 16 + lr;
                int slot = (kc * 4 + g) ^ (lr & 7);
                bf16x8 b = *reinterpret_cast<bf16x8*>(sVc + ((d << 7) | (slot << 4)));
                acc[dj] = __builtin_amdgcn_mfma_f32_16x16x32_bf16(pa[kc], b, acc[dj], 0, 0, 0);
            }
        }
    }
    #pragma unroll
    for (int r = 0; r < 4; ++r) {
        float inv = 1.0f / l_run[r];
        int row = qrow_base + r;
        #pragma unroll
        for (int dj = 0; dj < 8; ++dj)
            Og[row * D_DIM + dj * 16 + lr] = acc[dj][r] * inv;
    }
}

// ---------------------------------------------------------------------------
extern "C" void kernel_launch(void* const* d_in, const int* in_sizes, int n_in,
                              void* d_out, int out_size, void* d_ws, size_t ws_size,
                              hipStream_t stream)
{
    const float* Qg = (const float*)d_in[0];
    const float* Kg = (const float*)d_in[1];
    const float* Vg = (const float*)d_in[2];
    float* Og = (float*)d_out;

    const size_t bfElems = (size_t)S_TOTAL * D_DIM;       // 1M elems, 2 MB bf16
    auto need = [bfElems](int n) -> size_t {
        size_t base = 3 * bfElems * 2;                    // Qbf,Kswz,Vtswz
        if (n > 1)
            base += (size_t)n * (bfElems * 2 + (size_t)S_TOTAL * 8);
        return base;
    };

    if (d_ws == nullptr || ws_size < need(1)) {
        hipLaunchKernelGGL(attn_f32, dim3(1, 128), dim3(256), 0, stream,
                           Qg, Kg, Vg, Og);
        return;
    }

    int nsplit = 16;
    while (nsplit > 1 && ws_size < need(nsplit)) nsplit >>= 1;

    unsigned short* Qbf  = (unsigned short*)d_ws;
    unsigned short* Kswz = Qbf + bfElems;
    unsigned short* Vt   = Kswz + bfElems;
    unsigned short* Opart = Vt + bfElems;
    float* mpart = (float*)(Opart + (size_t)nsplit * bfElems);
    float* lpart = mpart + (size_t)nsplit * S_TOTAL;

    hipLaunchKernelGGL(prep_q, dim3(1024), dim3(256), 0, stream, Qg, Qbf);
    hipLaunchKernelGGL(prep_k, dim3(512),  dim3(256), 0, stream, Kg, Kswz);
    hipLaunchKernelGGL(prep_v, dim3(256),  dim3(256), 0, stream, Vg, Vt);

    hipLaunchKernelGGL(attn32, dim3(nsplit, QT64), dim3(256), 0, stream,
                       Qbf, Kswz, Vt, Og, Opart, mpart, lpart);
    if (nsplit > 1)
        hipLaunchKernelGGL(attn_merge2, dim3(S_TOTAL / 16), dim3(256), 0, stream,
                           Opart, mpart, lpart, Og, nsplit);
}